// Round 8
// baseline (284.059 us; speedup 1.0000x reference)
//
#include <hip/hip_runtime.h>

// Problem constants
#define B_  32
#define C_  64
#define H_  64
#define W_  64
#define O_  128
#define LAT 64
#define HW  (H_*W_)
#define KJ  (O_*C_*9)      // 73728
#define KTOT 576           // C_*9, GEMM K per batch
#define NKS 18             // K steps of 32
#define SLAB 4096          // bf16 elems per k-slab of kbf2 (O_*32)

typedef __bf16 bf16x8 __attribute__((ext_vector_type(8)));
typedef float  f32x4  __attribute__((ext_vector_type(4)));

// ===========================================================================
// MEASUREMENT ROUND (resubmission — round-7 bench never ran: broker timeout).
// Real work identical to r6 (148.6us baseline). Probe generations repeat
// each stage into dead scratch so each stage's dispatch outranks the ~41us
// poison fills in the top-5 and we finally get direct per-stage durations
// + conv's counters.
//   transpose: grid x8  -> dur ~= 8*t1
//   kergen   : grid x8  -> dur ~= 8*t3
//   conv     : grid x3  -> dur ~= 3*t4  (+ MfmaUtil/Occ/FETCH/WRITE/conflicts)
// Probe writes go to scratch (identical values across gens -> benign races).
// Real outputs are written exactly once -> correctness unchanged.
// ===========================================================================

// ---------------------------------------------------------------------------
// Stage 1: transpose x -> xT[b][h][w][c] bf16, plus per-(b,h,c) row sums.
// ---------------------------------------------------------------------------
__global__ __launch_bounds__(256) void transpose_gap(const float* __restrict__ x,
                                                     __bf16* __restrict__ xT,
                                                     float* __restrict__ gap_part,
                                                     __bf16* __restrict__ xT_s,
                                                     float* __restrict__ gap_s) {
    int bid = blockIdx.x;
    if (bid >= 2048) { xT = xT_s; gap_part = gap_s; }   // probe generations
    int bh = bid & 2047;
    int b = bh >> 6, h = bh & 63;
    __shared__ float lt[64 * 65];
    int t = threadIdx.x;
    int cc0 = t >> 4, w4 = (t & 15) * 4;

    #pragma unroll
    for (int i = 0; i < 4; i++) {
        int cc = cc0 + 16 * i;
        float4 v = *(const float4*)(x + (((size_t)(b * C_ + cc) * H_) + h) * W_ + w4);
        lt[cc * 65 + w4 + 0] = v.x;
        lt[cc * 65 + w4 + 1] = v.y;
        lt[cc * 65 + w4 + 2] = v.z;
        lt[cc * 65 + w4 + 3] = v.w;
        float s = (v.x + v.y) + (v.z + v.w);
        s += __shfl_xor(s, 1); s += __shfl_xor(s, 2);
        s += __shfl_xor(s, 4); s += __shfl_xor(s, 8);
        if ((t & 15) == 0) gap_part[h * 2048 + b * 64 + cc] = s;
    }
    __syncthreads();

    __bf16* dst = xT + ((size_t)(b * H_ + h) * W_) * C_;
    #pragma unroll
    for (int k = 0; k < 2; k++) {
        int chunk = t + k * 256;
        int w = chunk >> 3, c8 = chunk & 7;
        __bf16 g[8];
        #pragma unroll
        for (int i = 0; i < 8; i++) g[i] = (__bf16)lt[(c8 * 8 + i) * 65 + w];
        *(int4*)(dst + w * C_ + c8 * 8) = *(int4*)g;
    }
}

// ---------------------------------------------------------------------------
// Stage 2: gap reduction + MLP. Writes f2 TRANSPOSED: f2t[l][b].
// ---------------------------------------------------------------------------
__global__ __launch_bounds__(64) void mlp_kernel(const float* __restrict__ gap_part,
                                                 const float* __restrict__ W1,
                                                 const float* __restrict__ b1,
                                                 const float* __restrict__ W2,
                                                 const float* __restrict__ b2,
                                                 float* __restrict__ f2t) {
    int b = blockIdx.x, j = threadIdx.x;
    float s = 0.f;
    #pragma unroll 16
    for (int h = 0; h < 64; h++) s += gap_part[h * 2048 + b * 64 + j];
    __shared__ float g[LAT], f1[LAT];
    g[j] = s * (1.0f / (float)HW);
    __syncthreads();
    float acc = b1[j];
    #pragma unroll 8
    for (int l = 0; l < LAT; l++) acc = fmaf(g[l], W1[l * LAT + j], acc);
    f1[j] = fmaxf(acc, 0.f);
    __syncthreads();
    float acc2 = b2[j];
    #pragma unroll 8
    for (int l = 0; l < LAT; l++) acc2 = fmaf(f1[l], W2[l * LAT + j], acc2);
    f2t[j * B_ + b] = fmaxf(acc2, 0.f);       // transposed store
}

// ---------------------------------------------------------------------------
// Stage 3: kernel generator -> bf16, FRAGMENT-LINEAR conv layout.
// kbf2 element (b, ks, o, kk) lives at
//   panel(b) + ks*4096 + (o>>4)*512 + (kk>>3)*128 + (o&15)*8 + (kk&7)
// ---------------------------------------------------------------------------
#define KGP2 592
__global__ __launch_bounds__(576) void kergen_kernel(const float* __restrict__ f2t,
                                                     const float* __restrict__ Wf,
                                                     const float* __restrict__ bfv,
                                                     __bf16* __restrict__ kbf2,
                                                     __bf16* __restrict__ kbf2_s) {
    int bid = blockIdx.x;
    if (bid >= 256) kbf2 = kbf2_s;             // probe generations
    int o = bid & 127, b0 = ((bid >> 7) & 1) * 16;
    int t = threadIdx.x;
    __shared__ __bf16 ltk[16 * KGP2];          // 18.9 KB

    int j = o * KTOT + t;
    float acc[16];
    float base = bfv[j];
    #pragma unroll
    for (int i = 0; i < 16; i++) acc[i] = base;

    for (int l8 = 0; l8 < LAT; l8 += 8) {
        float w8[8];
        #pragma unroll
        for (int i = 0; i < 8; i++) w8[i] = Wf[(size_t)(l8 + i) * KJ + j];
        #pragma unroll
        for (int i = 0; i < 8; i++) {
            #pragma unroll
            for (int bb = 0; bb < 16; bb++)
                acc[bb] = fmaf(f2t[(l8 + i) * B_ + b0 + bb], w8[i], acc[bb]);
        }
    }

    int c = t / 9, tap = t - c * 9;
    int tpp = (tap * 2 + (c >> 5)) * 32 + (c & 31);
    #pragma unroll
    for (int bb = 0; bb < 16; bb++) ltk[bb * KGP2 + tpp] = (__bf16)acc[bb];
    __syncthreads();
    int ks = t >> 5, kk = t & 31;
    int OB = (o >> 6) * 4 + ((o >> 4) & 3);
    int OL = o & 15;
    size_t foff = (size_t)ks * SLAB + OB * 512 + (kk >> 3) * 128 + OL * 8 + (kk & 7);
    #pragma unroll
    for (int bb = 0; bb < 16; bb++)
        kbf2[(size_t)(b0 + bb) * (NKS * SLAB) + foff] = ltk[bb * KGP2 + t];
}

// ---------------------------------------------------------------------------
// Stage 4: implicit-GEMM MFMA conv. M=128 o, N=256 px (4 rows), K=576.
// A through LDS via async global_load_lds double-buffer (r6 structure).
// ---------------------------------------------------------------------------
#define CPAD 72
#define ROWE (66 * CPAD)

__global__ __launch_bounds__(512, 4) void conv_mfma(const __bf16* __restrict__ xT,
                                                    const __bf16* __restrict__ kbf2,
                                                    float* __restrict__ out,
                                                    float* __restrict__ out_s) {
    int n   = blockIdx.x;                      // 0..1535 (>=512 are probes)
    if (n >= 512) out = out_s;
    n &= 511;
    int xcd = n & 7;
    int idx = n >> 3;                          // 0..63 within XCD
    int b   = xcd * 4 + (idx >> 4);            // 4 batches per XCD
    int h0  = (idx & 15) * 4;                  // 4 output rows per block
    __shared__ __bf16 xs[6 * ROWE];            // 57 KB
    __shared__ __bf16 Ab[2][SLAB];             // 16 KB A double-buffer
    int tid = threadIdx.x;

    const __bf16* kbA = kbf2 + (size_t)b * (NKS * SLAB);

    // prologue: DMA slab 0 into Ab[0] (lands before the staging barrier)
    __builtin_amdgcn_global_load_lds(
        reinterpret_cast<const unsigned int*>(kbA + tid * 8),
        reinterpret_cast<unsigned int*>(&Ab[0][(tid >> 6) * 512]), 16, 0, 0);

    // zero halo columns w'=0 and w'=65 for all 6 staged rows
    if (tid < 96) {
        int r = tid >> 4, which = (tid >> 3) & 1, c8 = tid & 7;
        *(int4*)(xs + (r * 66 + which * 65) * CPAD + c8 * 8) = int4{0, 0, 0, 0};
    }
    // zero OOB rows (edge blocks only)
    if (h0 == 0) {
        for (int i = tid; i < ROWE / 8; i += 512)
            *(int4*)(xs + i * 8) = int4{0, 0, 0, 0};
    }
    if (h0 == H_ - 4) {
        for (int i = tid; i < ROWE / 8; i += 512)
            *(int4*)(xs + 5 * ROWE + i * 8) = int4{0, 0, 0, 0};
    }

    // stage rows h0-1 .. h0+4
    #pragma unroll
    for (int i = 0; i < 6; i++) {
        int c8 = tid & 7, w = (tid >> 3) & 63, r = i;
        int hh = h0 - 1 + r;
        if ((unsigned)hh < (unsigned)H_) {
            int4 v = *(const int4*)(xT + ((size_t)(b * H_ + hh) * W_ + w) * C_ + c8 * 8);
            *(int4*)(xs + (r * 66 + w + 1) * CPAD + c8 * 8) = v;
        }
    }
    __syncthreads();                            // drains DMA(slab0) too

    int wave = tid >> 6, lane = tid & 63;
    int wi = wave >> 2, wj = wave & 3;         // wi: M-half, wj: h-row 0..3
    int l15 = lane & 15, quad = lane >> 4;

    f32x4 acc[4][4];
    #pragma unroll
    for (int mt = 0; mt < 4; mt++)
        #pragma unroll
        for (int nt = 0; nt < 4; nt++)
            acc[mt][nt] = (f32x4){0.f, 0.f, 0.f, 0.f};

    #pragma unroll
    for (int ks = 0; ks < NKS; ks++) {
        // issue next slab's DMA first: max separation from the drain
        if (ks < NKS - 1) {
            __builtin_amdgcn_global_load_lds(
                reinterpret_cast<const unsigned int*>(kbA + (ks + 1) * SLAB + tid * 8),
                reinterpret_cast<unsigned int*>(&Ab[(ks + 1) & 1][(tid >> 6) * 512]),
                16, 0, 0);
        }
        // A fragments: lane*16-contiguous ds_read_b128, conflict-free
        const __bf16* As = &Ab[ks & 1][(wi * 4) * 512 + lane * 8];
        bf16x8 afrag[4];
        #pragma unroll
        for (int mt = 0; mt < 4; mt++)
            afrag[mt] = *(const bf16x8*)(As + mt * 512);

        int tap = ks >> 1;                     // compile-time after unroll
        int kh = tap / 3, kw = tap - kh * 3;
        int c0 = (ks & 1) * 32;
        const __bf16* Bb = xs + ((wj + kh) * 66 + kw + l15) * CPAD + c0 + quad * 8;
        #pragma unroll
        for (int nt = 0; nt < 4; nt++) {
            bf16x8 bfrag = *(const bf16x8*)(Bb + nt * 16 * CPAD);
            #pragma unroll
            for (int mt = 0; mt < 4; mt++)
                acc[mt][nt] = __builtin_amdgcn_mfma_f32_16x16x32_bf16(
                    afrag[mt], bfrag, acc[mt][nt], 0, 0, 0);
        }
        if (ks < NKS - 1) __syncthreads();     // vmcnt drain: slab ks+1 ready
    }

    // epilogue: D row = quad*4 + reg, col = l15
    int h = h0 + wj;
    float* ob = out + ((size_t)b * O_ + wi * 64) * HW + h * W_;
    #pragma unroll
    for (int mt = 0; mt < 4; mt++) {
        #pragma unroll
        for (int nt = 0; nt < 4; nt++) {
            int w = nt * 16 + l15;
            #pragma unroll
            for (int r = 0; r < 4; r++) {
                int oo = mt * 16 + quad * 4 + r;
                ob[(size_t)oo * HW + w] = acc[mt][nt][r];
            }
        }
    }
}

// ---------------------------------------------------------------------------
// Launch (4 kernels; probe generations appended to 3 of them)
// ---------------------------------------------------------------------------
extern "C" void kernel_launch(void* const* d_in, const int* in_sizes, int n_in,
                              void* d_out, int out_size, void* d_ws, size_t ws_size,
                              hipStream_t stream) {
    const float* x  = (const float*)d_in[0];
    const float* W1 = (const float*)d_in[1];
    const float* b1 = (const float*)d_in[2];
    const float* W2 = (const float*)d_in[3];
    const float* b2 = (const float*)d_in[4];
    const float* Wf = (const float*)d_in[5];
    const float* bf = (const float*)d_in[6];
    float* out = (float*)d_out;

    // Workspace layout (real):
    //   gap_part : 64*32*64 f32      @ 0         (512 KB)
    //   f2t      : 64*32 f32         @ 512 KB    (8 KB)
    //   kbf2     : 32*18*4096 bf16   @ 528 KB    (4.5 MiB)
    //   xT       : 32*64*64*64 bf16  @ ~5.0 MiB  (16 MiB)
    // Probe scratch (dead writes; ws is 256 MiB per the harness fills):
    //   xT_s   @ 32 MiB,  gap_s @ 54 MiB,  kbf2_s @ 64 MiB,  out_s @ 96 MiB
    float*  gap_part = (float*)d_ws;
    float*  f2t      = (float*)((char*)d_ws + 524288);
    __bf16* kbf2     = (__bf16*)((char*)d_ws + 540672);
    __bf16* xT       = (__bf16*)((char*)d_ws + 540672 + (size_t)B_ * NKS * SLAB * 2);
    __bf16* xT_s     = (__bf16*)((char*)d_ws + 33554432);
    float*  gap_s    = (float*) ((char*)d_ws + 56623104);
    __bf16* kbf2_s   = (__bf16*)((char*)d_ws + 67108864);
    float*  out_s    = (float*) ((char*)d_ws + 100663296);

    transpose_gap<<<2048 * 8, 256, 0, stream>>>(x, xT, gap_part, xT_s, gap_s);
    mlp_kernel<<<B_, 64, 0, stream>>>(gap_part, W1, b1, W2, b2, f2t);
    kergen_kernel<<<256 * 8, 576, 0, stream>>>(f2t, Wf, bf, kbf2, kbf2_s);
    conv_mfma<<<512 * 3, 512, 0, stream>>>(xT, kbf2, out, out_s);
}

// Round 9
// 180.802 us; speedup vs baseline: 1.5711x; 1.5711x over previous
//
#include <hip/hip_runtime.h>

// Problem constants
#define B_  32
#define C_  64
#define H_  64
#define W_  64
#define O_  128
#define LAT 64
#define HW  (H_*W_)
#define KJ  (O_*C_*9)      // 73728
#define KTOT 576           // C_*9, GEMM K per batch
#define NKS 18             // K steps of 32
#define SLAB 4096          // bf16 elems per k-slab of kbf2 (O_*32)

typedef __bf16 bf16x8 __attribute__((ext_vector_type(8)));
typedef float  f32x4  __attribute__((ext_vector_type(4)));

// ===========================================================================
// ROUND 9. r8 probe round measured: t4(conv)=22.8us (was 47.5 in r0 -> the
// async-DMA rewrite worked), t1+t3=12.8us (at memory floor), serial
// additivity of extra work confirmed. conv's remaining gap to its ~13us
// overlap floor is the per-K-step __syncthreads vmcnt(0) drain of the
// just-issued DMA (one ~300cy MFMA phase < L3 ~500cy latency -> stall at
// all 17 barriers). Fix = T4: 3-deep A-buffer, counted s_waitcnt vmcnt(1)
// + raw s_barrier (+sched_barrier(0) fence, rule 18) -> oldest DMA waited,
// newest flies across the barrier; 2 phases (~600cy) of latency cover.
// transpose/kergen probes stripped (measured, at-floor); conv x3 probe
// KEPT to verify this sync-structure edit directly in the top-5 counters.
// ===========================================================================

// ---------------------------------------------------------------------------
// Stage 1: transpose x -> xT[b][h][w][c] bf16, plus per-(b,h,c) row sums.
// ---------------------------------------------------------------------------
__global__ __launch_bounds__(256) void transpose_gap(const float* __restrict__ x,
                                                     __bf16* __restrict__ xT,
                                                     float* __restrict__ gap_part) {
    int bh = blockIdx.x, b = bh >> 6, h = bh & 63;
    __shared__ float lt[64 * 65];
    int t = threadIdx.x;
    int cc0 = t >> 4, w4 = (t & 15) * 4;

    #pragma unroll
    for (int i = 0; i < 4; i++) {
        int cc = cc0 + 16 * i;
        float4 v = *(const float4*)(x + (((size_t)(b * C_ + cc) * H_) + h) * W_ + w4);
        lt[cc * 65 + w4 + 0] = v.x;
        lt[cc * 65 + w4 + 1] = v.y;
        lt[cc * 65 + w4 + 2] = v.z;
        lt[cc * 65 + w4 + 3] = v.w;
        float s = (v.x + v.y) + (v.z + v.w);
        s += __shfl_xor(s, 1); s += __shfl_xor(s, 2);
        s += __shfl_xor(s, 4); s += __shfl_xor(s, 8);
        if ((t & 15) == 0) gap_part[h * 2048 + b * 64 + cc] = s;
    }
    __syncthreads();

    __bf16* dst = xT + ((size_t)(b * H_ + h) * W_) * C_;
    #pragma unroll
    for (int k = 0; k < 2; k++) {
        int chunk = t + k * 256;
        int w = chunk >> 3, c8 = chunk & 7;
        __bf16 g[8];
        #pragma unroll
        for (int i = 0; i < 8; i++) g[i] = (__bf16)lt[(c8 * 8 + i) * 65 + w];
        *(int4*)(dst + w * C_ + c8 * 8) = *(int4*)g;
    }
}

// ---------------------------------------------------------------------------
// Stage 2: gap reduction + MLP. Writes f2 TRANSPOSED: f2t[l][b].
// ---------------------------------------------------------------------------
__global__ __launch_bounds__(64) void mlp_kernel(const float* __restrict__ gap_part,
                                                 const float* __restrict__ W1,
                                                 const float* __restrict__ b1,
                                                 const float* __restrict__ W2,
                                                 const float* __restrict__ b2,
                                                 float* __restrict__ f2t) {
    int b = blockIdx.x, j = threadIdx.x;
    float s = 0.f;
    #pragma unroll 16
    for (int h = 0; h < 64; h++) s += gap_part[h * 2048 + b * 64 + j];
    __shared__ float g[LAT], f1[LAT];
    g[j] = s * (1.0f / (float)HW);
    __syncthreads();
    float acc = b1[j];
    #pragma unroll 8
    for (int l = 0; l < LAT; l++) acc = fmaf(g[l], W1[l * LAT + j], acc);
    f1[j] = fmaxf(acc, 0.f);
    __syncthreads();
    float acc2 = b2[j];
    #pragma unroll 8
    for (int l = 0; l < LAT; l++) acc2 = fmaf(f1[l], W2[l * LAT + j], acc2);
    f2t[j * B_ + b] = fmaxf(acc2, 0.f);       // transposed store
}

// ---------------------------------------------------------------------------
// Stage 3: kernel generator -> bf16, FRAGMENT-LINEAR conv layout.
// kbf2 element (b, ks, o, kk) lives at
//   panel(b) + ks*4096 + (o>>4)*512 + (kk>>3)*128 + (o&15)*8 + (kk&7)
// ---------------------------------------------------------------------------
#define KGP2 592
__global__ __launch_bounds__(576) void kergen_kernel(const float* __restrict__ f2t,
                                                     const float* __restrict__ Wf,
                                                     const float* __restrict__ bfv,
                                                     __bf16* __restrict__ kbf2) {
    int bid = blockIdx.x;
    int o = bid & 127, b0 = (bid >> 7) * 16;
    int t = threadIdx.x;
    __shared__ __bf16 ltk[16 * KGP2];          // 18.9 KB

    int j = o * KTOT + t;
    float acc[16];
    float base = bfv[j];
    #pragma unroll
    for (int i = 0; i < 16; i++) acc[i] = base;

    for (int l8 = 0; l8 < LAT; l8 += 8) {
        float w8[8];
        #pragma unroll
        for (int i = 0; i < 8; i++) w8[i] = Wf[(size_t)(l8 + i) * KJ + j];
        #pragma unroll
        for (int i = 0; i < 8; i++) {
            #pragma unroll
            for (int bb = 0; bb < 16; bb++)
                acc[bb] = fmaf(f2t[(l8 + i) * B_ + b0 + bb], w8[i], acc[bb]);
        }
    }

    int c = t / 9, tap = t - c * 9;
    int tpp = (tap * 2 + (c >> 5)) * 32 + (c & 31);
    #pragma unroll
    for (int bb = 0; bb < 16; bb++) ltk[bb * KGP2 + tpp] = (__bf16)acc[bb];
    __syncthreads();
    int ks = t >> 5, kk = t & 31;
    int OB = (o >> 6) * 4 + ((o >> 4) & 3);
    int OL = o & 15;
    size_t foff = (size_t)ks * SLAB + OB * 512 + (kk >> 3) * 128 + OL * 8 + (kk & 7);
    #pragma unroll
    for (int bb = 0; bb < 16; bb++)
        kbf2[(size_t)(b0 + bb) * (NKS * SLAB) + foff] = ltk[bb * KGP2 + t];
}

// ---------------------------------------------------------------------------
// Stage 4: implicit-GEMM MFMA conv. M=128 o, N=256 px (4 rows), K=576.
// ROUND-9 CHANGE: 3-deep A double->triple buffer + counted-vmcnt barriers.
//   prologue: DMA slab0->Ab[0], slab1->Ab[1]; stage __syncthreads drains.
//   step ks: issue DMA slab ks+2 -> Ab[(ks+2)%3]; ds_read A from Ab[ks%3];
//            16 MFMA; then s_waitcnt vmcnt(1) (oldest DMA = slab ks+1
//            landed, newest stays in flight ACROSS the raw s_barrier)
//            + sched_barrier(0) fence (rule 18).
//   WAR safe: slab ks+2 overwrites the buffer last read at step ks-1,
//   published by the end-of-(ks-1) barrier.
// LDS: xs 57.0KB + Ab 24.6KB = 81.6KB -> 80KB alloc x2 = 160KB exact fit.
// ---------------------------------------------------------------------------
#define CPAD 72
#define ROWE (66 * CPAD)

__global__ __launch_bounds__(512, 4) void conv_mfma(const __bf16* __restrict__ xT,
                                                    const __bf16* __restrict__ kbf2,
                                                    float* __restrict__ out,
                                                    float* __restrict__ out_s) {
    int n   = blockIdx.x;                      // 0..1535 (>=512 are probes)
    if (n >= 512) out = out_s;
    n &= 511;
    int xcd = n & 7;
    int idx = n >> 3;                          // 0..63 within XCD
    int b   = xcd * 4 + (idx >> 4);            // 4 batches per XCD
    int h0  = (idx & 15) * 4;                  // 4 output rows per block
    __shared__ __bf16 xs[6 * ROWE];            // 57.0 KB
    __shared__ __bf16 Ab[3][SLAB];             // 24.6 KB A triple-buffer
    int tid = threadIdx.x;

    const __bf16* kbA = kbf2 + (size_t)b * (NKS * SLAB);

    // prologue: DMA slabs 0 and 1 (both land before the staging barrier)
    __builtin_amdgcn_global_load_lds(
        reinterpret_cast<const unsigned int*>(kbA + tid * 8),
        reinterpret_cast<unsigned int*>(&Ab[0][(tid >> 6) * 512]), 16, 0, 0);
    __builtin_amdgcn_global_load_lds(
        reinterpret_cast<const unsigned int*>(kbA + SLAB + tid * 8),
        reinterpret_cast<unsigned int*>(&Ab[1][(tid >> 6) * 512]), 16, 0, 0);

    // zero halo columns w'=0 and w'=65 for all 6 staged rows
    if (tid < 96) {
        int r = tid >> 4, which = (tid >> 3) & 1, c8 = tid & 7;
        *(int4*)(xs + (r * 66 + which * 65) * CPAD + c8 * 8) = int4{0, 0, 0, 0};
    }
    // zero OOB rows (edge blocks only)
    if (h0 == 0) {
        for (int i = tid; i < ROWE / 8; i += 512)
            *(int4*)(xs + i * 8) = int4{0, 0, 0, 0};
    }
    if (h0 == H_ - 4) {
        for (int i = tid; i < ROWE / 8; i += 512)
            *(int4*)(xs + 5 * ROWE + i * 8) = int4{0, 0, 0, 0};
    }

    // stage rows h0-1 .. h0+4
    #pragma unroll
    for (int i = 0; i < 6; i++) {
        int c8 = tid & 7, w = (tid >> 3) & 63, r = i;
        int hh = h0 - 1 + r;
        if ((unsigned)hh < (unsigned)H_) {
            int4 v = *(const int4*)(xT + ((size_t)(b * H_ + hh) * W_ + w) * C_ + c8 * 8);
            *(int4*)(xs + (r * 66 + w + 1) * CPAD + c8 * 8) = v;
        }
    }
    __syncthreads();                            // full drain: slabs 0,1 + xs

    int wave = tid >> 6, lane = tid & 63;
    int wi = wave >> 2, wj = wave & 3;         // wi: M-half, wj: h-row 0..3
    int l15 = lane & 15, quad = lane >> 4;

    f32x4 acc[4][4];
    #pragma unroll
    for (int mt = 0; mt < 4; mt++)
        #pragma unroll
        for (int nt = 0; nt < 4; nt++)
            acc[mt][nt] = (f32x4){0.f, 0.f, 0.f, 0.f};

    #pragma unroll
    for (int ks = 0; ks < NKS; ks++) {
        // issue slab ks+2 into the buffer retired at end of step ks-1
        if (ks < NKS - 2) {
            __builtin_amdgcn_global_load_lds(
                reinterpret_cast<const unsigned int*>(kbA + (ks + 2) * SLAB + tid * 8),
                reinterpret_cast<unsigned int*>(&Ab[(ks + 2) % 3][(tid >> 6) * 512]),
                16, 0, 0);
        }
        // A fragments: lane*16-contiguous ds_read_b128, conflict-free
        const __bf16* As = &Ab[ks % 3][(wi * 4) * 512 + lane * 8];
        bf16x8 afrag[4];
        #pragma unroll
        for (int mt = 0; mt < 4; mt++)
            afrag[mt] = *(const bf16x8*)(As + mt * 512);

        int tap = ks >> 1;                     // compile-time after unroll
        int kh = tap / 3, kw = tap - kh * 3;
        int c0 = (ks & 1) * 32;
        const __bf16* Bb = xs + ((wj + kh) * 66 + kw + l15) * CPAD + c0 + quad * 8;
        #pragma unroll
        for (int nt = 0; nt < 4; nt++) {
            bf16x8 bfrag = *(const bf16x8*)(Bb + nt * 16 * CPAD);
            #pragma unroll
            for (int mt = 0; mt < 4; mt++)
                acc[mt][nt] = __builtin_amdgcn_mfma_f32_16x16x32_bf16(
                    afrag[mt], bfrag, acc[mt][nt], 0, 0, 0);
        }
        // counted-vmcnt barrier: oldest DMA (slab ks+1) landed, newest flies
        if (ks < NKS - 2) {
            asm volatile("s_waitcnt vmcnt(1)" ::: "memory");
            __builtin_amdgcn_s_barrier();
            __builtin_amdgcn_sched_barrier(0);
        } else if (ks == NKS - 2) {
            asm volatile("s_waitcnt vmcnt(0)" ::: "memory");
            __builtin_amdgcn_s_barrier();
            __builtin_amdgcn_sched_barrier(0);
        }
    }

    // epilogue: D row = quad*4 + reg, col = l15
    int h = h0 + wj;
    float* ob = out + ((size_t)b * O_ + wi * 64) * HW + h * W_;
    #pragma unroll
    for (int mt = 0; mt < 4; mt++) {
        #pragma unroll
        for (int nt = 0; nt < 4; nt++) {
            int w = nt * 16 + l15;
            #pragma unroll
            for (int r = 0; r < 4; r++) {
                int oo = mt * 16 + quad * 4 + r;
                ob[(size_t)oo * HW + w] = acc[mt][nt][r];
            }
        }
    }
}

// ---------------------------------------------------------------------------
// Launch (4 kernels; conv keeps the x3 probe for direct verification)
// ---------------------------------------------------------------------------
extern "C" void kernel_launch(void* const* d_in, const int* in_sizes, int n_in,
                              void* d_out, int out_size, void* d_ws, size_t ws_size,
                              hipStream_t stream) {
    const float* x  = (const float*)d_in[0];
    const float* W1 = (const float*)d_in[1];
    const float* b1 = (const float*)d_in[2];
    const float* W2 = (const float*)d_in[3];
    const float* b2 = (const float*)d_in[4];
    const float* Wf = (const float*)d_in[5];
    const float* bf = (const float*)d_in[6];
    float* out = (float*)d_out;

    // Workspace layout (real):
    //   gap_part : 64*32*64 f32      @ 0         (512 KB)
    //   f2t      : 64*32 f32         @ 512 KB    (8 KB)
    //   kbf2     : 32*18*4096 bf16   @ 528 KB    (4.5 MiB)
    //   xT       : 32*64*64*64 bf16  @ ~5.0 MiB  (16 MiB)
    // Probe scratch: out_s @ 96 MiB (64 MB; ws is 256 MiB per harness fills)
    float*  gap_part = (float*)d_ws;
    float*  f2t      = (float*)((char*)d_ws + 524288);
    __bf16* kbf2     = (__bf16*)((char*)d_ws + 540672);
    __bf16* xT       = (__bf16*)((char*)d_ws + 540672 + (size_t)B_ * NKS * SLAB * 2);
    float*  out_s    = (float*) ((char*)d_ws + 100663296);

    transpose_gap<<<B_ * H_, 256, 0, stream>>>(x, xT, gap_part);
    mlp_kernel<<<B_, 64, 0, stream>>>(gap_part, W1, b1, W2, b2, f2t);
    kergen_kernel<<<256, 576, 0, stream>>>(f2t, Wf, bf, kbf2);
    conv_mfma<<<512 * 3, 512, 0, stream>>>(xT, kbf2, out, out_s);
}

// Round 13
// 153.427 us; speedup vs baseline: 1.8514x; 1.1784x over previous
//
#include <hip/hip_runtime.h>

// Problem constants
#define B_  32
#define C_  64
#define H_  64
#define W_  64
#define O_  128
#define LAT 64
#define HW  (H_*W_)
#define KJ  (O_*C_*9)      // 73728
#define KTOT 576           // C_*9, GEMM K per batch
#define NKS 18             // K steps of 32
#define SLAB 4096          // bf16 elems per k-slab of kbf2 (O_*32)

typedef __bf16 bf16x8 __attribute__((ext_vector_type(8)));
typedef float  f32x4  __attribute__((ext_vector_type(4)));

// ===========================================================================
// ROUND 13 = ROUND 12 RESUBMISSION (broker timeout, no data; identical src).
// Round-10 geometry, PRODUCTION (no probes). r9 measured t4=20.6us (MFMA
// busy ~= 9.3us floor; 12.4us = unoverlapped 64MB epilogue, single-
// generation lockstep). This config: 2-output-row tiles -> 1024 blocks =
// 2 resident x 2 generations/CU; gen-1 epilogues overlap gen-2 K-loops.
// Wave split (wi x wj x nw) keeps per-output LDS traffic identical
// (B-reuse 4). Counted-vmcnt triple-buffer DMA pipeline verbatim from r9
// (measured: MfmaUtil 33->40, passed). LDS 38.0+24.6 = 62.6KB -> 2 blk/CU.
// Readout vs r9's implied no-probe 139.6us: ~135 = stagger works;
// ~140 = neutral (still banks counted-vmcnt gain); >=148 = revert.
// ===========================================================================

// ---------------------------------------------------------------------------
// Stage 1: transpose x -> xT[b][h][w][c] bf16, plus per-(b,h,c) row sums.
// ---------------------------------------------------------------------------
__global__ __launch_bounds__(256) void transpose_gap(const float* __restrict__ x,
                                                     __bf16* __restrict__ xT,
                                                     float* __restrict__ gap_part) {
    int bh = blockIdx.x, b = bh >> 6, h = bh & 63;
    __shared__ float lt[64 * 65];
    int t = threadIdx.x;
    int cc0 = t >> 4, w4 = (t & 15) * 4;

    #pragma unroll
    for (int i = 0; i < 4; i++) {
        int cc = cc0 + 16 * i;
        float4 v = *(const float4*)(x + (((size_t)(b * C_ + cc) * H_) + h) * W_ + w4);
        lt[cc * 65 + w4 + 0] = v.x;
        lt[cc * 65 + w4 + 1] = v.y;
        lt[cc * 65 + w4 + 2] = v.z;
        lt[cc * 65 + w4 + 3] = v.w;
        float s = (v.x + v.y) + (v.z + v.w);
        s += __shfl_xor(s, 1); s += __shfl_xor(s, 2);
        s += __shfl_xor(s, 4); s += __shfl_xor(s, 8);
        if ((t & 15) == 0) gap_part[h * 2048 + b * 64 + cc] = s;
    }
    __syncthreads();

    __bf16* dst = xT + ((size_t)(b * H_ + h) * W_) * C_;
    #pragma unroll
    for (int k = 0; k < 2; k++) {
        int chunk = t + k * 256;
        int w = chunk >> 3, c8 = chunk & 7;
        __bf16 g[8];
        #pragma unroll
        for (int i = 0; i < 8; i++) g[i] = (__bf16)lt[(c8 * 8 + i) * 65 + w];
        *(int4*)(dst + w * C_ + c8 * 8) = *(int4*)g;
    }
}

// ---------------------------------------------------------------------------
// Stage 2: gap reduction + MLP. Writes f2 TRANSPOSED: f2t[l][b].
// ---------------------------------------------------------------------------
__global__ __launch_bounds__(64) void mlp_kernel(const float* __restrict__ gap_part,
                                                 const float* __restrict__ W1,
                                                 const float* __restrict__ b1,
                                                 const float* __restrict__ W2,
                                                 const float* __restrict__ b2,
                                                 float* __restrict__ f2t) {
    int b = blockIdx.x, j = threadIdx.x;
    float s = 0.f;
    #pragma unroll 16
    for (int h = 0; h < 64; h++) s += gap_part[h * 2048 + b * 64 + j];
    __shared__ float g[LAT], f1[LAT];
    g[j] = s * (1.0f / (float)HW);
    __syncthreads();
    float acc = b1[j];
    #pragma unroll 8
    for (int l = 0; l < LAT; l++) acc = fmaf(g[l], W1[l * LAT + j], acc);
    f1[j] = fmaxf(acc, 0.f);
    __syncthreads();
    float acc2 = b2[j];
    #pragma unroll 8
    for (int l = 0; l < LAT; l++) acc2 = fmaf(f1[l], W2[l * LAT + j], acc2);
    f2t[j * B_ + b] = fmaxf(acc2, 0.f);       // transposed store
}

// ---------------------------------------------------------------------------
// Stage 3: kernel generator -> bf16, FRAGMENT-LINEAR conv layout.
// kbf2 element (b, ks, o, kk) lives at
//   panel(b) + ks*4096 + (o>>4)*512 + (kk>>3)*128 + (o&15)*8 + (kk&7)
// ---------------------------------------------------------------------------
#define KGP2 592
__global__ __launch_bounds__(576) void kergen_kernel(const float* __restrict__ f2t,
                                                     const float* __restrict__ Wf,
                                                     const float* __restrict__ bfv,
                                                     __bf16* __restrict__ kbf2) {
    int bid = blockIdx.x;
    int o = bid & 127, b0 = (bid >> 7) * 16;
    int t = threadIdx.x;
    __shared__ __bf16 ltk[16 * KGP2];          // 18.9 KB

    int j = o * KTOT + t;
    float acc[16];
    float base = bfv[j];
    #pragma unroll
    for (int i = 0; i < 16; i++) acc[i] = base;

    for (int l8 = 0; l8 < LAT; l8 += 8) {
        float w8[8];
        #pragma unroll
        for (int i = 0; i < 8; i++) w8[i] = Wf[(size_t)(l8 + i) * KJ + j];
        #pragma unroll
        for (int i = 0; i < 8; i++) {
            #pragma unroll
            for (int bb = 0; bb < 16; bb++)
                acc[bb] = fmaf(f2t[(l8 + i) * B_ + b0 + bb], w8[i], acc[bb]);
        }
    }

    int c = t / 9, tap = t - c * 9;
    int tpp = (tap * 2 + (c >> 5)) * 32 + (c & 31);
    #pragma unroll
    for (int bb = 0; bb < 16; bb++) ltk[bb * KGP2 + tpp] = (__bf16)acc[bb];
    __syncthreads();
    int ks = t >> 5, kk = t & 31;
    int OB = (o >> 6) * 4 + ((o >> 4) & 3);
    int OL = o & 15;
    size_t foff = (size_t)ks * SLAB + OB * 512 + (kk >> 3) * 128 + OL * 8 + (kk & 7);
    #pragma unroll
    for (int bb = 0; bb < 16; bb++)
        kbf2[(size_t)(b0 + bb) * (NKS * SLAB) + foff] = ltk[bb * KGP2 + t];
}

// ---------------------------------------------------------------------------
// Stage 4: implicit-GEMM MFMA conv. M=128 o, N=128 px (2 rows), K=576.
// 1024 blocks = 2 resident x 2 generations/CU for epilogue/K-loop overlap.
// Waves: wi (M-half, mt<4) x wj (row) x nw (N-half, nt<2). acc[4][2].
// A via LDS triple-buffer DMA + counted s_waitcnt vmcnt(1) + raw s_barrier.
// ---------------------------------------------------------------------------
#define CPAD 72
#define ROWE (66 * CPAD)

__global__ __launch_bounds__(512, 4) void conv_mfma(const __bf16* __restrict__ xT,
                                                    const __bf16* __restrict__ kbf2,
                                                    float* __restrict__ out) {
    int n   = blockIdx.x;                      // 0..1023
    int xcd = n & 7;
    int idx = n >> 3;                          // 0..127 within XCD
    int b   = xcd * 4 + (idx >> 5);            // 4 batches per XCD
    int h0  = (idx & 31) * 2;                  // 2 output rows per block
    __shared__ __bf16 xs[4 * ROWE];            // 38.0 KB (4 staged rows)
    __shared__ __bf16 Ab[3][SLAB];             // 24.6 KB A triple-buffer
    int tid = threadIdx.x;

    const __bf16* kbA = kbf2 + (size_t)b * (NKS * SLAB);

    // prologue: DMA slabs 0 and 1 (both land before the staging barrier)
    __builtin_amdgcn_global_load_lds(
        reinterpret_cast<const unsigned int*>(kbA + tid * 8),
        reinterpret_cast<unsigned int*>(&Ab[0][(tid >> 6) * 512]), 16, 0, 0);
    __builtin_amdgcn_global_load_lds(
        reinterpret_cast<const unsigned int*>(kbA + SLAB + tid * 8),
        reinterpret_cast<unsigned int*>(&Ab[1][(tid >> 6) * 512]), 16, 0, 0);

    // zero halo columns w'=0 and w'=65 for all 4 staged rows
    if (tid < 64) {
        int r = tid >> 4, which = (tid >> 3) & 1, c8 = tid & 7;
        *(int4*)(xs + (r * 66 + which * 65) * CPAD + c8 * 8) = int4{0, 0, 0, 0};
    }
    // zero OOB rows (edge blocks only)
    if (h0 == 0) {
        for (int i = tid; i < ROWE / 8; i += 512)
            *(int4*)(xs + i * 8) = int4{0, 0, 0, 0};
    }
    if (h0 == H_ - 2) {
        for (int i = tid; i < ROWE / 8; i += 512)
            *(int4*)(xs + 3 * ROWE + i * 8) = int4{0, 0, 0, 0};
    }

    // stage rows h0-1 .. h0+2 (2048 int4 chunks over 512 threads)
    #pragma unroll
    for (int i = 0; i < 4; i++) {
        int chunk = tid + i * 512;
        int c8 = chunk & 7, w = (chunk >> 3) & 63, r = chunk >> 9;
        int hh = h0 - 1 + r;
        if ((unsigned)hh < (unsigned)H_) {
            int4 v = *(const int4*)(xT + ((size_t)(b * H_ + hh) * W_ + w) * C_ + c8 * 8);
            *(int4*)(xs + (r * 66 + w + 1) * CPAD + c8 * 8) = v;
        }
    }
    __syncthreads();                            // full drain: slabs 0,1 + xs

    int wave = tid >> 6, lane = tid & 63;
    int wi = wave >> 2;                        // M-half (mt<4)
    int wj = (wave >> 1) & 1;                  // output row
    int nw = wave & 1;                         // N-half (32 w each)
    int l15 = lane & 15, quad = lane >> 4;

    f32x4 acc[4][2];
    #pragma unroll
    for (int mt = 0; mt < 4; mt++)
        #pragma unroll
        for (int nt = 0; nt < 2; nt++)
            acc[mt][nt] = (f32x4){0.f, 0.f, 0.f, 0.f};

    #pragma unroll
    for (int ks = 0; ks < NKS; ks++) {
        // issue slab ks+2 into the buffer retired at end of step ks-1
        if (ks < NKS - 2) {
            __builtin_amdgcn_global_load_lds(
                reinterpret_cast<const unsigned int*>(kbA + (ks + 2) * SLAB + tid * 8),
                reinterpret_cast<unsigned int*>(&Ab[(ks + 2) % 3][(tid >> 6) * 512]),
                16, 0, 0);
        }
        // A fragments: lane*16-contiguous ds_read_b128, conflict-free
        const __bf16* As = &Ab[ks % 3][(wi * 4) * 512 + lane * 8];
        bf16x8 afrag[4];
        #pragma unroll
        for (int mt = 0; mt < 4; mt++)
            afrag[mt] = *(const bf16x8*)(As + mt * 512);

        int tap = ks >> 1;                     // compile-time after unroll
        int kh = tap / 3, kw = tap - kh * 3;
        int c0 = (ks & 1) * 32;
        const __bf16* Bb = xs + ((wj + kh) * 66 + kw + nw * 32 + l15) * CPAD + c0 + quad * 8;
        #pragma unroll
        for (int nt = 0; nt < 2; nt++) {
            bf16x8 bfrag = *(const bf16x8*)(Bb + nt * 16 * CPAD);
            #pragma unroll
            for (int mt = 0; mt < 4; mt++)
                acc[mt][nt] = __builtin_amdgcn_mfma_f32_16x16x32_bf16(
                    afrag[mt], bfrag, acc[mt][nt], 0, 0, 0);
        }
        // counted-vmcnt barrier: oldest DMA (slab ks+1) landed, newest flies
        if (ks < NKS - 2) {
            asm volatile("s_waitcnt vmcnt(1)" ::: "memory");
            __builtin_amdgcn_s_barrier();
            __builtin_amdgcn_sched_barrier(0);
        } else if (ks == NKS - 2) {
            asm volatile("s_waitcnt vmcnt(0)" ::: "memory");
            __builtin_amdgcn_s_barrier();
            __builtin_amdgcn_sched_barrier(0);
        }
    }

    // epilogue: D row = quad*4 + reg, col = l15
    int h = h0 + wj;
    float* ob = out + ((size_t)b * O_ + wi * 64) * HW + h * W_ + nw * 32;
    #pragma unroll
    for (int mt = 0; mt < 4; mt++) {
        #pragma unroll
        for (int nt = 0; nt < 2; nt++) {
            int w = nt * 16 + l15;
            #pragma unroll
            for (int r = 0; r < 4; r++) {
                int oo = mt * 16 + quad * 4 + r;
                ob[(size_t)oo * HW + w] = acc[mt][nt][r];
            }
        }
    }
}

// ---------------------------------------------------------------------------
// Launch (4 kernels)
// ---------------------------------------------------------------------------
extern "C" void kernel_launch(void* const* d_in, const int* in_sizes, int n_in,
                              void* d_out, int out_size, void* d_ws, size_t ws_size,
                              hipStream_t stream) {
    const float* x  = (const float*)d_in[0];
    const float* W1 = (const float*)d_in[1];
    const float* b1 = (const float*)d_in[2];
    const float* W2 = (const float*)d_in[3];
    const float* b2 = (const float*)d_in[4];
    const float* Wf = (const float*)d_in[5];
    const float* bf = (const float*)d_in[6];
    float* out = (float*)d_out;

    // Workspace layout:
    //   gap_part : 64*32*64 f32      @ 0         (512 KB)
    //   f2t      : 64*32 f32         @ 512 KB    (8 KB)
    //   kbf2     : 32*18*4096 bf16   @ 528 KB    (4.5 MiB)
    //   xT       : 32*64*64*64 bf16  @ ~5.0 MiB  (16 MiB)
    float*  gap_part = (float*)d_ws;
    float*  f2t      = (float*)((char*)d_ws + 524288);
    __bf16* kbf2     = (__bf16*)((char*)d_ws + 540672);
    __bf16* xT       = (__bf16*)((char*)d_ws + 540672 + (size_t)B_ * NKS * SLAB * 2);

    transpose_gap<<<B_ * H_, 256, 0, stream>>>(x, xT, gap_part);
    mlp_kernel<<<B_, 64, 0, stream>>>(gap_part, W1, b1, W2, b2, f2t);
    kergen_kernel<<<256, 576, 0, stream>>>(f2t, Wf, bf, kbf2);
    conv_mfma<<<1024, 512, 0, stream>>>(xT, kbf2, out);
}